// Round 2
// baseline (17658.626 us; speedup 1.0000x reference)
//
#include <hip/hip_runtime.h>
#include <math.h>

// Problem constants
#define HDIM   300
#define G3     900          // 3*H
#define VSZ    19495
#define NOUNC  10000
#define PRONC  82
#define VERBC  6555
#define TENC   512
#define TDEC   2048

// Recurrence lane geometry
#define LANES  5            // 4 encoders + 1 decoder
#define KWG    15           // workgroups per lane
#define SLICE  20           // h outputs per WG (KWG*SLICE == HDIM)
#define ROWSW  60           // Whh rows per WG (3 gates * SLICE)
#define CHUNK  75           // K elements per thread (4 threads per row)
#define FLAGSTRIDE 16

// GEMM tile
#define BLK 64
#define KC  75

#define AGENT_SCOPE __HIP_MEMORY_SCOPE_AGENT

static __device__ __forceinline__ int ld_acq_i(int* p) {
    return __hip_atomic_load(p, __ATOMIC_ACQUIRE, AGENT_SCOPE);
}
static __device__ __forceinline__ void st_rel_i(int* p, int v) {
    __hip_atomic_store(p, v, __ATOMIC_RELEASE, AGENT_SCOPE);
}
static __device__ __forceinline__ float ld_f(const float* p) {
    return __hip_atomic_load((float*)p, __ATOMIC_RELAXED, AGENT_SCOPE);
}
static __device__ __forceinline__ void st_f(float* p, float v) {
    __hip_atomic_store(p, v, __ATOMIC_RELAXED, AGENT_SCOPE);
}

// ---------------------------------------------------------------------------
// Concatenate the 4 encoder id arrays into one [2048] list
// ---------------------------------------------------------------------------
__global__ void prep_ids_kernel(const int* __restrict__ a, const int* __restrict__ b,
                                const int* __restrict__ c, const int* __restrict__ d,
                                int* __restrict__ out) {
    int t = blockIdx.x * blockDim.x + threadIdx.x;
    if (t >= 4 * TENC) return;
    int e = t >> 9, i = t & 511;
    const int* src = (e == 0) ? a : (e == 1) ? b : (e == 2) ? c : d;
    out[t] = src[i];
}

// ---------------------------------------------------------------------------
// Bucket decoder rows by tag (order within bucket irrelevant)
// ---------------------------------------------------------------------------
__global__ void bucket_kernel(const int* __restrict__ tags, int* __restrict__ lists,
                              int* __restrict__ counts) {
    __shared__ int cnt[4];
    int tid = threadIdx.x;
    if (tid < 4) cnt[tid] = 0;
    __syncthreads();
    for (int t = tid; t < TDEC; t += blockDim.x) {
        int g = tags[t];
        if (g < 0 || g > 3) g = 3;   // reference: 0,1,2, else
        int pos = atomicAdd(&cnt[g], 1);
        lists[g * TDEC + pos] = t;
    }
    __syncthreads();
    if (tid < 4) counts[tid] = cnt[tid];
}

// ---------------------------------------------------------------------------
// Generic gathered GEMM: out[orow][col] = A[ridx][:] . W[col][:] + bias[col]
// K = 300 fixed. A rows gathered via aidx (or identity). If scatter, out row
// = aidx[t]; else out row = t. Columns >= Nreal (and < Nstore) get zeros
// (covers the head zero-padding so no d_out memset is needed).
// ---------------------------------------------------------------------------
__global__ __launch_bounds__(256)
void gemm_gather_kernel(const float* __restrict__ A, const float* __restrict__ W,
                        const float* __restrict__ bias,
                        const int* __restrict__ aidx, const int* __restrict__ count_ptr,
                        int M_total, int scatter, int Nreal, int Nstore, int out_ld,
                        float* __restrict__ out) {
    int M = count_ptr ? *count_ptr : M_total;
    int rb = blockIdx.y * BLK;
    if (rb >= M) return;
    int cb = blockIdx.x * BLK;
    if (cb >= Nstore) return;

    int tid = threadIdx.x;
    int tx = tid & 15, ty = tid >> 4;

    __shared__ int ridx[BLK];
    __shared__ int orow[BLK];
    if (tid < BLK) {
        int t = rb + tid;
        int gi = 0, oo = -1;
        if (t < M) {
            gi = aidx ? aidx[t] : t;
            oo = scatter ? gi : t;
        }
        ridx[tid] = gi;
        orow[tid] = oo;
    }
    __syncthreads();

    if (cb >= Nreal) {
        // pure zero-fill tile (padding region of masked heads)
        #pragma unroll
        for (int i = 0; i < 4; i++) {
            int o = orow[ty * 4 + i];
            if (o < 0) continue;
            #pragma unroll
            for (int j = 0; j < 4; j++) {
                int col = cb + tx * 4 + j;
                if (col < Nstore) out[(size_t)o * out_ld + col] = 0.f;
            }
        }
        return;
    }

    __shared__ float As[BLK][KC + 1];
    __shared__ float Bs[BLK][KC + 1];
    float acc[4][4] = {{0.f}};

    for (int kc = 0; kc < HDIM; kc += KC) {
        for (int e = tid; e < BLK * KC; e += 256) {
            int r = e / KC, k = e - r * KC;
            float v = 0.f;
            if (rb + r < M) v = A[(size_t)ridx[r] * HDIM + kc + k];
            As[r][k] = v;
        }
        for (int e = tid; e < BLK * KC; e += 256) {
            int r = e / KC, k = e - r * KC;
            int col = cb + r;
            float v = 0.f;
            if (col < Nreal) v = W[(size_t)col * HDIM + kc + k];
            Bs[r][k] = v;
        }
        __syncthreads();
        #pragma unroll 5
        for (int k = 0; k < KC; k++) {
            float a0 = As[ty * 4 + 0][k], a1 = As[ty * 4 + 1][k];
            float a2 = As[ty * 4 + 2][k], a3 = As[ty * 4 + 3][k];
            float b0 = Bs[tx * 4 + 0][k], b1 = Bs[tx * 4 + 1][k];
            float b2 = Bs[tx * 4 + 2][k], b3 = Bs[tx * 4 + 3][k];
            acc[0][0] += a0 * b0; acc[0][1] += a0 * b1; acc[0][2] += a0 * b2; acc[0][3] += a0 * b3;
            acc[1][0] += a1 * b0; acc[1][1] += a1 * b1; acc[1][2] += a1 * b2; acc[1][3] += a1 * b3;
            acc[2][0] += a2 * b0; acc[2][1] += a2 * b1; acc[2][2] += a2 * b2; acc[2][3] += a2 * b3;
            acc[3][0] += a3 * b0; acc[3][1] += a3 * b1; acc[3][2] += a3 * b2; acc[3][3] += a3 * b3;
        }
        __syncthreads();
    }

    #pragma unroll
    for (int i = 0; i < 4; i++) {
        int o = orow[ty * 4 + i];
        if (o < 0) continue;
        #pragma unroll
        for (int j = 0; j < 4; j++) {
            int col = cb + tx * 4 + j;
            if (col < Nstore) {
                float v = 0.f;
                if (col < Nreal) v = acc[i][j] + bias[col];
                out[(size_t)o * out_ld + col] = v;
            }
        }
    }
}

// ---------------------------------------------------------------------------
// Persistent GRU recurrence. 5 lanes (4 encoders + decoder), KWG workgroups
// per lane, Whh slice register-resident, h exchanged via agent-scope
// atomics + monotonic release/acquire flags. bid%8==lane keeps a lane's WGs
// on one XCD (perf only; agent scope gives correctness anywhere).
// Protocol: flag f == v+base means h version v is ready at hbuf parity v&1.
// Encoders: base=0, h0 zeroed by host memset. Decoder: base=1 (version 0 =
// 'hidden', published by each WG after encoders finish).
// ---------------------------------------------------------------------------
__global__ __launch_bounds__(256)
void gru_rnn_kernel(const float* __restrict__ enc_xg, const float* __restrict__ dec_xg,
                    const float* __restrict__ encWhh, const float* __restrict__ encbhh,
                    const float* __restrict__ decWhh, const float* __restrict__ decbhh,
                    const float* __restrict__ stateW, const float* __restrict__ stateb,
                    float* __restrict__ hs, float* hbuf, int* flags) {
    int bid = blockIdx.x;
    int lane = bid & 7;
    int w = bid >> 3;
    if (lane >= LANES || w >= KWG) return;

    const bool isdec = (lane == 4);
    const float* Whh = isdec ? decWhh : encWhh;
    const float* bhh = isdec ? decbhh : encbhh;
    const float* xg  = isdec ? dec_xg : (enc_xg + (size_t)lane * TENC * G3);
    const int T     = isdec ? TDEC : TENC;
    const int base  = isdec ? 1 : 0;
    float* myh      = hbuf + lane * (2 * HDIM);
    int*   myflags  = flags + lane * FLAGSTRIDE;

    const int tid = threadIdx.x;
    const int lr  = tid >> 2;        // local row 0..63 (valid < ROWSW)
    const int c   = tid & 3;         // K-chunk 0..3

    __shared__ float h_lds[4 * 76];  // 4 chunks of 75, padded to 76
    __shared__ float gh_lds[ROWSW];
    __shared__ float bhh_lds[ROWSW];

    // register-resident Whh slice: row grow, cols [c*75, c*75+75)
    float wreg[CHUNK];
    if (lr < ROWSW) {
        int gate = lr / SLICE, j = lr % SLICE;
        int grow = gate * HDIM + w * SLICE + j;
        const float* src = Whh + (size_t)grow * HDIM + c * CHUNK;
        #pragma unroll
        for (int i = 0; i < CHUNK; i++) wreg[i] = src[i];
    }
    if (tid < ROWSW) {
        int gate = tid / SLICE, j = tid % SLICE;
        bhh_lds[tid] = bhh[gate * HDIM + w * SLICE + j];
    }
    __syncthreads();

    if (isdec) {
        // wait for all 4 encoder lanes to publish version 512
        if (tid < 64) {
            for (;;) {
                int f = 0x7fffffff;
                if (tid < 4 * KWG)
                    f = ld_acq_i(&flags[(tid / KWG) * FLAGSTRIDE + (tid % KWG)]);
                if (__all(f >= TENC)) break;
                __builtin_amdgcn_s_sleep(8);
            }
        }
        __syncthreads();
        // hidden = concat(h_verb,h_pron,h_noun,h_sen) @ state_W.T + state_b
        // concat chunk c2 == encoder lane c2's final h (parity 512&1 == 0)
        if (tid < 4 * SLICE) {
            int jj = tid >> 2, c2 = tid & 3;
            const float* henc = hbuf + c2 * (2 * HDIM);   // parity 0
            const float* wrow = stateW + (size_t)(w * SLICE + jj) * (4 * HDIM) + c2 * HDIM;
            float a = 0.f;
            for (int i = 0; i < HDIM; i++) a += wrow[i] * ld_f(&henc[i]);
            a += __shfl_xor(a, 1);
            a += __shfl_xor(a, 2);
            if (c2 == 0) st_f(&myh[w * SLICE + jj], a + stateb[w * SLICE + jj]);
            __threadfence();
        }
        __syncthreads();
        if (tid == 0) st_rel_i(&myflags[w], base);   // version 0 (hidden) ready
    }

    for (int s = 0; s < T; ++s) {
        // 1. wait for version s from every WG in this lane
        if (tid < 64) {
            for (;;) {
                int f = 0x7fffffff;
                if (tid < KWG) f = ld_acq_i(&myflags[tid]);
                if (__all(f >= s + base)) break;
            }
        }
        __syncthreads();
        // 2. stage full h (version s) into LDS, chunk-padded
        {
            const float* hin = myh + (s & 1) * HDIM;
            for (int t = tid; t < HDIM; t += 256) {
                float hv = ld_f(&hin[t]);
                h_lds[(t / 75) * 76 + (t % 75)] = hv;
            }
        }
        __syncthreads();
        // 3. partial matvec: gh[grow] partial over K chunk c
        if (lr < ROWSW) {
            const float* hc = &h_lds[c * 76];
            float a0 = 0.f, a1 = 0.f, a2 = 0.f, a3 = 0.f;
            #pragma unroll
            for (int i = 0; i < 72; i += 4) {
                a0 += wreg[i + 0] * hc[i + 0];
                a1 += wreg[i + 1] * hc[i + 1];
                a2 += wreg[i + 2] * hc[i + 2];
                a3 += wreg[i + 3] * hc[i + 3];
            }
            a0 += wreg[72] * hc[72];
            a1 += wreg[73] * hc[73];
            a2 += wreg[74] * hc[74];
            float acc = (a0 + a1) + (a2 + a3);
            acc += __shfl_xor(acc, 1);
            acc += __shfl_xor(acc, 2);
            if (c == 0) gh_lds[lr] = acc;
        }
        __syncthreads();
        // 4. gates + h update for this WG's SLICE outputs (full precision
        //    expf/tanhf: only 20 lanes run this; error must not compound
        //    over 2048 sequential steps)
        if (tid < SLICE) {
            int jj = tid;
            float ghr = gh_lds[jj]             + bhh_lds[jj];
            float ghz = gh_lds[SLICE + jj]     + bhh_lds[SLICE + jj];
            float ghn = gh_lds[2 * SLICE + jj] + bhh_lds[2 * SLICE + jj];
            const float* xrow = xg + (size_t)s * G3 + w * SLICE + jj;
            float xr = xrow[0], xz = xrow[HDIM], xn = xrow[2 * HDIM];
            float r = 1.f / (1.f + expf(-(xr + ghr)));
            float z = 1.f / (1.f + expf(-(xz + ghz)));
            float n  = tanhf(xn + r * ghn);
            int gj = w * SLICE + jj;
            float hold = h_lds[(gj / 75) * 76 + (gj % 75)];
            float hnew = (1.f - z) * n + z * hold;
            st_f(&myh[((s + 1) & 1) * HDIM + gj], hnew);
            if (isdec) hs[(size_t)s * HDIM + gj] = hnew;
            __threadfence();
        }
        __syncthreads();
        if (tid == 0) st_rel_i(&myflags[w], s + 1 + base);
    }
}

// ---------------------------------------------------------------------------
// Host launch
// ---------------------------------------------------------------------------
extern "C" void kernel_launch(void* const* d_in, const int* in_sizes, int n_in,
                              void* d_out, int out_size, void* d_ws, size_t ws_size,
                              hipStream_t stream) {
    const int* verb_in = (const int*)d_in[0];
    const int* pron_in = (const int*)d_in[1];
    const int* noun_in = (const int*)d_in[2];
    const int* sen_in  = (const int*)d_in[3];
    const int* tgt_in  = (const int*)d_in[4];
    const int* tgt_tag = (const int*)d_in[5];
    const float* emb      = (const float*)d_in[6];
    const float* enc_Wih  = (const float*)d_in[7];
    const float* enc_Whh  = (const float*)d_in[8];
    const float* enc_bih  = (const float*)d_in[9];
    const float* enc_bhh  = (const float*)d_in[10];
    const float* dec_Wih  = (const float*)d_in[11];
    const float* dec_Whh  = (const float*)d_in[12];
    const float* dec_bih  = (const float*)d_in[13];
    const float* dec_bhh  = (const float*)d_in[14];
    const float* state_W  = (const float*)d_in[15];
    const float* state_b  = (const float*)d_in[16];
    const float* noun_W   = (const float*)d_in[17];
    const float* noun_b   = (const float*)d_in[18];
    const float* verb_W   = (const float*)d_in[19];
    const float* verb_b   = (const float*)d_in[20];
    const float* pron_W   = (const float*)d_in[21];
    const float* pron_b   = (const float*)d_in[22];
    const float* sen_W    = (const float*)d_in[23];
    const float* sen_b    = (const float*)d_in[24];

    float* out = (float*)d_out;
    char* ws = (char*)d_ws;

    // ws layout (bytes); total ~17.3 MB
    float* enc_xg  = (float*)(ws + 0);                       // 4*512*900 f = 7372800 B
    float* dec_xg  = (float*)(ws + 7372800);                 // 2048*900 f  = 7372800 B
    float* hs      = (float*)(ws + 14745600);                // 2048*300 f  = 2457600 B
    int*   enc_ids = (int*)  (ws + 17203200);                // 2048 i      = 8192 B
    int*   lists   = (int*)  (ws + 17211392);                // 4*2048 i    = 32768 B
    int*   counts  = (int*)  (ws + 17244160);                // pad to 64 B
    char*  syncreg = ws + 17244224;                          // flags + hbuf
    int*   flags   = (int*)syncreg;                          // 5*16 i = 320 B
    float* hbuf    = (float*)(syncreg + 320);                // 5*2*300 f = 12000 B
    const size_t SYNC_BYTES = 320 + 12000;

    // zero flags + h buffers (ws is re-poisoned 0xAA before every launch)
    hipMemsetAsync(syncreg, 0, SYNC_BYTES, stream);

    prep_ids_kernel<<<8, 256, 0, stream>>>(verb_in, pron_in, noun_in, sen_in, enc_ids);

    // xg = emb[ids] @ Wih.T + bih   (enc: 4x512 rows; dec: 2048 rows)
    gemm_gather_kernel<<<dim3(15, 32), 256, 0, stream>>>(
        emb, enc_Wih, enc_bih, enc_ids, nullptr, 4 * TENC, 0, G3, G3, G3, enc_xg);
    gemm_gather_kernel<<<dim3(15, 32), 256, 0, stream>>>(
        emb, dec_Wih, dec_bih, tgt_in, nullptr, TDEC, 0, G3, G3, G3, dec_xg);

    bucket_kernel<<<1, 1024, 0, stream>>>(tgt_tag, lists, counts);

    gru_rnn_kernel<<<8 * KWG, 256, 0, stream>>>(
        enc_xg, dec_xg, enc_Whh, enc_bhh, dec_Whh, dec_bhh,
        state_W, state_b, hs, hbuf, flags);

    // heads: rows bucketed by tag; tiles beyond the head width write zeros,
    // so no d_out memset is required (every element written exactly once)
    const float* headW[4] = {noun_W, verb_W, pron_W, sen_W};
    const float* headB[4] = {noun_b, verb_b, pron_b, sen_b};
    const int    headN[4] = {NOUNC, VERBC, PRONC, VSZ};
    for (int g = 0; g < 4; ++g) {
        gemm_gather_kernel<<<dim3((VSZ + BLK - 1) / BLK, TDEC / BLK), 256, 0, stream>>>(
            hs, headW[g], headB[g], lists + g * TDEC, counts + g,
            TDEC, 1, headN[g], VSZ, VSZ, out);
    }
}

// Round 4
// 7747.459 us; speedup vs baseline: 2.2793x; 2.2793x over previous
//
#include <hip/hip_runtime.h>
#include <math.h>

// Problem constants
#define HDIM   300
#define G3     900          // 3*H
#define VSZ    19495
#define NOUNC  10000
#define PRONC  82
#define VERBC  6555
#define TENC   512
#define TDEC   2048

// Recurrence lane geometry
#define LANES  5            // 4 encoders + 1 decoder
#define KWG    15           // workgroups per lane
#define SLICE  20           // h outputs per WG (KWG*SLICE == HDIM)
#define ROWSW  60           // Whh rows per WG (3 gates * SLICE)
#define CHUNK  75           // K elements per thread (4 threads per row)
#define WLD    301          // padded LDS row stride for Whh slice

// GEMM tile
#define BLK 64
#define KC  75

#define AGENT_SCOPE __HIP_MEMORY_SCOPE_AGENT
typedef unsigned long long u64;

// Tagged-word handoff: one 8B word = (version<<32 | float bits). Relaxed
// agent-scope atomics only — no acquire/release (those cost whole-L2
// inv/writeback per op on multi-XCD gfx950). Tag travels atomically with
// the value, so no ordering/fences are needed anywhere in the hot loop.
static __device__ __forceinline__ u64 ld_tag(const u64* p) {
    return __hip_atomic_load((u64*)p, __ATOMIC_RELAXED, AGENT_SCOPE);
}
static __device__ __forceinline__ void st_tag(u64* p, float v, int ver) {
    u64 wd = ((u64)(unsigned)ver << 32) | (u64)__float_as_uint(v);
    __hip_atomic_store(p, wd, __ATOMIC_RELAXED, AGENT_SCOPE);
}
static __device__ __forceinline__ float poll_word(const u64* p, int want) {
    for (;;) {
        u64 wd = ld_tag(p);
        if ((int)(wd >> 32) >= want) return __uint_as_float((unsigned)wd);
    }
}
static __device__ __forceinline__ float poll_word_sleep(const u64* p, int want) {
    for (;;) {
        u64 wd = ld_tag(p);
        if ((int)(wd >> 32) >= want) return __uint_as_float((unsigned)wd);
        __builtin_amdgcn_s_sleep(16);
    }
}

// ---------------------------------------------------------------------------
// Concatenate the 4 encoder id arrays into one [2048] list
// ---------------------------------------------------------------------------
__global__ void prep_ids_kernel(const int* __restrict__ a, const int* __restrict__ b,
                                const int* __restrict__ c, const int* __restrict__ d,
                                int* __restrict__ out) {
    int t = blockIdx.x * blockDim.x + threadIdx.x;
    if (t >= 4 * TENC) return;
    int e = t >> 9, i = t & 511;
    const int* src = (e == 0) ? a : (e == 1) ? b : (e == 2) ? c : d;
    out[t] = src[i];
}

// ---------------------------------------------------------------------------
// Bucket decoder rows by tag (order within bucket irrelevant)
// ---------------------------------------------------------------------------
__global__ void bucket_kernel(const int* __restrict__ tags, int* __restrict__ lists,
                              int* __restrict__ counts) {
    __shared__ int cnt[4];
    int tid = threadIdx.x;
    if (tid < 4) cnt[tid] = 0;
    __syncthreads();
    for (int t = tid; t < TDEC; t += blockDim.x) {
        int g = tags[t];
        if (g < 0 || g > 3) g = 3;   // reference: 0,1,2, else
        int pos = atomicAdd(&cnt[g], 1);
        lists[g * TDEC + pos] = t;
    }
    __syncthreads();
    if (tid < 4) counts[tid] = cnt[tid];
}

// ---------------------------------------------------------------------------
// Generic gathered GEMM: out[orow][col] = A[ridx][:] . W[col][:] + bias[col]
// ---------------------------------------------------------------------------
__global__ __launch_bounds__(256)
void gemm_gather_kernel(const float* __restrict__ A, const float* __restrict__ W,
                        const float* __restrict__ bias,
                        const int* __restrict__ aidx, const int* __restrict__ count_ptr,
                        int M_total, int scatter, int Nreal, int Nstore, int out_ld,
                        float* __restrict__ out) {
    int M = count_ptr ? *count_ptr : M_total;
    int rb = blockIdx.y * BLK;
    if (rb >= M) return;
    int cb = blockIdx.x * BLK;
    if (cb >= Nstore) return;

    int tid = threadIdx.x;
    int tx = tid & 15, ty = tid >> 4;

    __shared__ int ridx[BLK];
    __shared__ int orow[BLK];
    if (tid < BLK) {
        int t = rb + tid;
        int gi = 0, oo = -1;
        if (t < M) {
            gi = aidx ? aidx[t] : t;
            oo = scatter ? gi : t;
        }
        ridx[tid] = gi;
        orow[tid] = oo;
    }
    __syncthreads();

    if (cb >= Nreal) {
        // pure zero-fill tile (padding region of masked heads)
        #pragma unroll
        for (int i = 0; i < 4; i++) {
            int o = orow[ty * 4 + i];
            if (o < 0) continue;
            #pragma unroll
            for (int j = 0; j < 4; j++) {
                int col = cb + tx * 4 + j;
                if (col < Nstore) out[(size_t)o * out_ld + col] = 0.f;
            }
        }
        return;
    }

    __shared__ float As[BLK][KC + 1];
    __shared__ float Bs[BLK][KC + 1];
    float acc[4][4] = {{0.f}};

    for (int kc = 0; kc < HDIM; kc += KC) {
        for (int e = tid; e < BLK * KC; e += 256) {
            int r = e / KC, k = e - r * KC;
            float v = 0.f;
            if (rb + r < M) v = A[(size_t)ridx[r] * HDIM + kc + k];
            As[r][k] = v;
        }
        for (int e = tid; e < BLK * KC; e += 256) {
            int r = e / KC, k = e - r * KC;
            int col = cb + r;
            float v = 0.f;
            if (col < Nreal) v = W[(size_t)col * HDIM + kc + k];
            Bs[r][k] = v;
        }
        __syncthreads();
        #pragma unroll 5
        for (int k = 0; k < KC; k++) {
            float a0 = As[ty * 4 + 0][k], a1 = As[ty * 4 + 1][k];
            float a2 = As[ty * 4 + 2][k], a3 = As[ty * 4 + 3][k];
            float b0 = Bs[tx * 4 + 0][k], b1 = Bs[tx * 4 + 1][k];
            float b2 = Bs[tx * 4 + 2][k], b3 = Bs[tx * 4 + 3][k];
            acc[0][0] += a0 * b0; acc[0][1] += a0 * b1; acc[0][2] += a0 * b2; acc[0][3] += a0 * b3;
            acc[1][0] += a1 * b0; acc[1][1] += a1 * b1; acc[1][2] += a1 * b2; acc[1][3] += a1 * b3;
            acc[2][0] += a2 * b0; acc[2][1] += a2 * b1; acc[2][2] += a2 * b2; acc[2][3] += a2 * b3;
            acc[3][0] += a3 * b0; acc[3][1] += a3 * b1; acc[3][2] += a3 * b2; acc[3][3] += a3 * b3;
        }
        __syncthreads();
    }

    #pragma unroll
    for (int i = 0; i < 4; i++) {
        int o = orow[ty * 4 + i];
        if (o < 0) continue;
        #pragma unroll
        for (int j = 0; j < 4; j++) {
            int col = cb + tx * 4 + j;
            if (col < Nstore) {
                float v = 0.f;
                if (col < Nreal) v = acc[i][j] + bias[col];
                out[(size_t)o * out_ld + col] = v;
            }
        }
    }
}

// ---------------------------------------------------------------------------
// Persistent GRU recurrence with tagged-word handoff.
// hbuf layout: [lane][parity][HDIM] u64 words, word = (ver<<32 | f32 bits).
// Encoders (lanes 0-3): step s consumes ver s (parity s&1), publishes s+1.
//   h0 = ver 0 = memset zeros.
// Decoder (lane 4): versions shifted +1 so memset ver-0 is never valid.
//   hidden published as ver 1; step s consumes ver s+1, publishes s+2.
// Overwrite safety: a WG writes ver v+1 (parity flip) only after observing
// ALL elements at ver v, which implies every WG consumed ver v-1 — the
// value being overwritten. Monotone versions -> no ABA.
// ---------------------------------------------------------------------------
__global__ __launch_bounds__(256)
void gru_rnn_kernel(const float* __restrict__ enc_xg, const float* __restrict__ dec_xg,
                    const float* __restrict__ encWhh, const float* __restrict__ encbhh,
                    const float* __restrict__ decWhh, const float* __restrict__ decbhh,
                    const float* __restrict__ stateW, const float* __restrict__ stateb,
                    float* __restrict__ hs, u64* hbuf) {
    int bid = blockIdx.x;
    int lane = bid & 7;
    int w = bid >> 3;
    if (lane >= LANES || w >= KWG) return;

    const bool isdec = (lane == 4);
    const float* Whh = isdec ? decWhh : encWhh;
    const float* bhh = isdec ? decbhh : encbhh;
    const float* xg  = isdec ? dec_xg : (enc_xg + (size_t)lane * TENC * G3);
    const int T  = isdec ? TDEC : TENC;
    const int vb = isdec ? 1 : 0;    // step s consumes ver s+vb, publishes s+vb+1
    u64* myh = hbuf + (size_t)lane * 2 * HDIM;

    const int tid = threadIdx.x;
    const int lr  = tid >> 2;        // local row 0..63 (valid < ROWSW)
    const int c   = tid & 3;         // K-chunk 0..3

    __shared__ float whh_lds[ROWSW * WLD];   // 72.2 KB, stride 301 vs banks
    __shared__ float h_lds[HDIM];
    __shared__ float gh_lds[ROWSW];
    __shared__ float bhh_lds[ROWSW];
    __shared__ float henc_lds[4][HDIM];      // decoder only

    // stage Whh slice into LDS: local row r -> global row (r/20)*300 + w*20 + r%20
    for (int e = tid; e < ROWSW * HDIM; e += 256) {
        int r = e / HDIM, col = e - r * HDIM;
        int grow = (r / SLICE) * HDIM + w * SLICE + (r % SLICE);
        whh_lds[r * WLD + col] = Whh[(size_t)grow * HDIM + col];
    }
    if (tid < ROWSW)
        bhh_lds[tid] = bhh[(tid / SLICE) * HDIM + w * SLICE + (tid % SLICE)];

    if (isdec) {
        // stage encoder finals (ver TENC, parity 0) into LDS
        for (int e = tid; e < 4 * HDIM; e += 256) {
            int l2 = e / HDIM, i = e - l2 * HDIM;
            henc_lds[l2][i] = poll_word_sleep(hbuf + (size_t)l2 * 2 * HDIM + i, TENC);
        }
        __syncthreads();
        // hidden = concat(verb,pron,noun,sen) @ state_W.T + state_b  (ver 1, parity 1)
        if (tid < 4 * SLICE) {
            int jj = tid >> 2, c2 = tid & 3;
            const float* wrow = stateW + (size_t)(w * SLICE + jj) * (4 * HDIM) + c2 * HDIM;
            float a = 0.f;
            for (int i = 0; i < HDIM; i++) a += wrow[i] * henc_lds[c2][i];
            a += __shfl_xor(a, 1);
            a += __shfl_xor(a, 2);
            if (c2 == 0)
                st_tag(&myh[1 * HDIM + w * SLICE + jj], a + stateb[w * SLICE + jj], 1);
        }
    }
    __syncthreads();   // whh_lds/bhh_lds ready

    for (int s = 0; s < T; ++s) {
        const int want = s + vb;
        // 1. poll+stage h (ver want) into LDS — self-validating tagged words
        {
            const u64* src = myh + (size_t)(want & 1) * HDIM;
            for (int t = tid; t < HDIM; t += 256)
                h_lds[t] = poll_word(&src[t], want);
        }
        __syncthreads();
        // 2. partial matvec: gh[lr] over K-chunk c (identical FLOP order to r1)
        if (lr < ROWSW) {
            const float* wr = &whh_lds[lr * WLD + c * CHUNK];
            const float* hc = &h_lds[c * CHUNK];
            float a0 = 0.f, a1 = 0.f, a2 = 0.f, a3 = 0.f;
            #pragma unroll
            for (int i = 0; i < 72; i += 4) {
                a0 += wr[i + 0] * hc[i + 0];
                a1 += wr[i + 1] * hc[i + 1];
                a2 += wr[i + 2] * hc[i + 2];
                a3 += wr[i + 3] * hc[i + 3];
            }
            a0 += wr[72] * hc[72];
            a1 += wr[73] * hc[73];
            a2 += wr[74] * hc[74];
            float acc = (a0 + a1) + (a2 + a3);
            acc += __shfl_xor(acc, 1);
            acc += __shfl_xor(acc, 2);
            if (c == 0) gh_lds[lr] = acc;
        }
        __syncthreads();
        // 3. gates + publish (20 lanes; full-precision expf/tanhf — error must
        //    not compound over 2048 sequential steps)
        if (tid < SLICE) {
            int jj = tid;
            float ghr = gh_lds[jj]             + bhh_lds[jj];
            float ghz = gh_lds[SLICE + jj]     + bhh_lds[SLICE + jj];
            float ghn = gh_lds[2 * SLICE + jj] + bhh_lds[2 * SLICE + jj];
            const float* xrow = xg + (size_t)s * G3 + w * SLICE + jj;
            float xr = xrow[0], xz = xrow[HDIM], xn = xrow[2 * HDIM];
            float r = 1.f / (1.f + expf(-(xr + ghr)));
            float z = 1.f / (1.f + expf(-(xz + ghz)));
            float n  = tanhf(xn + r * ghn);
            int gj = w * SLICE + jj;
            float hold = h_lds[gj];
            float hnew = (1.f - z) * n + z * hold;
            st_tag(&myh[(size_t)((want + 1) & 1) * HDIM + gj], hnew, want + 1);
            if (isdec) hs[(size_t)s * HDIM + gj] = hnew;
        }
        __syncthreads();   // protect h_lds/gh_lds before next stage
    }
}

// ---------------------------------------------------------------------------
// Host launch
// ---------------------------------------------------------------------------
extern "C" void kernel_launch(void* const* d_in, const int* in_sizes, int n_in,
                              void* d_out, int out_size, void* d_ws, size_t ws_size,
                              hipStream_t stream) {
    const int* verb_in = (const int*)d_in[0];
    const int* pron_in = (const int*)d_in[1];
    const int* noun_in = (const int*)d_in[2];
    const int* sen_in  = (const int*)d_in[3];
    const int* tgt_in  = (const int*)d_in[4];
    const int* tgt_tag = (const int*)d_in[5];
    const float* emb      = (const float*)d_in[6];
    const float* enc_Wih  = (const float*)d_in[7];
    const float* enc_Whh  = (const float*)d_in[8];
    const float* enc_bih  = (const float*)d_in[9];
    const float* enc_bhh  = (const float*)d_in[10];
    const float* dec_Wih  = (const float*)d_in[11];
    const float* dec_Whh  = (const float*)d_in[12];
    const float* dec_bih  = (const float*)d_in[13];
    const float* dec_bhh  = (const float*)d_in[14];
    const float* state_W  = (const float*)d_in[15];
    const float* state_b  = (const float*)d_in[16];
    const float* noun_W   = (const float*)d_in[17];
    const float* noun_b   = (const float*)d_in[18];
    const float* verb_W   = (const float*)d_in[19];
    const float* verb_b   = (const float*)d_in[20];
    const float* pron_W   = (const float*)d_in[21];
    const float* pron_b   = (const float*)d_in[22];
    const float* sen_W    = (const float*)d_in[23];
    const float* sen_b    = (const float*)d_in[24];

    float* out = (float*)d_out;
    char* ws = (char*)d_ws;

    // ws layout (bytes)
    float* enc_xg  = (float*)(ws + 0);                       // 4*512*900 f = 7372800 B
    float* dec_xg  = (float*)(ws + 7372800);                 // 2048*900 f  = 7372800 B
    float* hs      = (float*)(ws + 14745600);                // 2048*300 f  = 2457600 B
    int*   enc_ids = (int*)  (ws + 17203200);                // 2048 i      = 8192 B
    int*   lists   = (int*)  (ws + 17211392);                // 4*2048 i    = 32768 B
    int*   counts  = (int*)  (ws + 17244160);                // 64 B pad
    u64*   hbuf    = (u64*)  (ws + 17244224);                // 5*2*300 u64 = 24000 B
    const size_t HBUF_BYTES = (size_t)LANES * 2 * HDIM * sizeof(u64);

    // zero tagged h buffers (ver 0 == encoder h0 == 0.0f); ws re-poisoned 0xAA
    hipMemsetAsync(hbuf, 0, HBUF_BYTES, stream);

    prep_ids_kernel<<<8, 256, 0, stream>>>(verb_in, pron_in, noun_in, sen_in, enc_ids);

    // xg = emb[ids] @ Wih.T + bih   (enc: 4x512 rows; dec: 2048 rows)
    gemm_gather_kernel<<<dim3(15, 32), 256, 0, stream>>>(
        emb, enc_Wih, enc_bih, enc_ids, nullptr, 4 * TENC, 0, G3, G3, G3, enc_xg);
    gemm_gather_kernel<<<dim3(15, 32), 256, 0, stream>>>(
        emb, dec_Wih, dec_bih, tgt_in, nullptr, TDEC, 0, G3, G3, G3, dec_xg);

    bucket_kernel<<<1, 1024, 0, stream>>>(tgt_tag, lists, counts);

    gru_rnn_kernel<<<8 * KWG, 256, 0, stream>>>(
        enc_xg, dec_xg, enc_Whh, enc_bhh, dec_Whh, dec_bhh,
        state_W, state_b, hs, hbuf);

    // heads: rows bucketed by tag; tiles beyond the head width write zeros,
    // so no d_out memset is required (every element written exactly once)
    const float* headW[4] = {noun_W, verb_W, pron_W, sen_W};
    const float* headB[4] = {noun_b, verb_b, pron_b, sen_b};
    const int    headN[4] = {NOUNC, VERBC, PRONC, VSZ};
    for (int g = 0; g < 4; ++g) {
        gemm_gather_kernel<<<dim3((VSZ + BLK - 1) / BLK, TDEC / BLK), 256, 0, stream>>>(
            hs, headW[g], headB[g], lists + g * TDEC, counts + g,
            TDEC, 1, headN[g], VSZ, VSZ, out);
    }
}

// Round 7
// 6496.664 us; speedup vs baseline: 2.7181x; 1.1925x over previous
//
#include <hip/hip_runtime.h>
#include <math.h>

// Problem constants
#define HDIM   300
#define G3     900          // 3*H
#define VSZ    19495
#define NOUNC  10000
#define PRONC  82
#define VERBC  6555
#define TENC   512
#define TDEC   2048

// Recurrence lane geometry
#define LANES  5            // 4 encoders + 1 decoder
#define KWG    15           // workgroups per lane
#define SLICE  20           // h outputs per WG (KWG*SLICE == HDIM)
#define ROWSW  60           // Whh rows per WG (3 gates * SLICE)
#define CHUNK  75           // K elements per thread (4 threads per row)
#define WLD    301          // padded LDS row stride for Whh slice

// GEMM tile
#define BLK 64
#define KC  75
#define PAD 77              // 77 mod 32 = 13 -> ~2-way banks (76 was 8-way)

// Head tile enumeration: 305 col-tiles (ceil(VSZ/64)) x 4 buckets per level
#define CT_ALL 305
#define TILES_PER_LVL (4 * CT_ALL)

#define AGENT_SCOPE __HIP_MEMORY_SCOPE_AGENT
typedef unsigned long long u64;

// Tagged-word handoff: one 8B word = (version<<32 | float bits). Relaxed
// agent-scope atomics only — no acquire/release (those cost whole-L2
// inv/writeback per op on multi-XCD gfx950). Tag travels atomically with
// the value, so no ordering/fences are needed anywhere in the hot loop.
static __device__ __forceinline__ u64 ld_tag(const u64* p) {
    return __hip_atomic_load((u64*)p, __ATOMIC_RELAXED, AGENT_SCOPE);
}
static __device__ __forceinline__ void st_tag(u64* p, float v, int ver) {
    u64 wd = ((u64)(unsigned)ver << 32) | (u64)__float_as_uint(v);
    __hip_atomic_store(p, wd, __ATOMIC_RELAXED, AGENT_SCOPE);
}
static __device__ __forceinline__ float poll_word(const u64* p, int want) {
    for (;;) {
        u64 wd = ld_tag(p);
        if ((int)(wd >> 32) >= want) return __uint_as_float((unsigned)wd);
    }
}
static __device__ __forceinline__ float poll_word_sleep(const u64* p, int want) {
    for (;;) {
        u64 wd = ld_tag(p);
        if ((int)(wd >> 32) >= want) return __uint_as_float((unsigned)wd);
        __builtin_amdgcn_s_sleep(16);
    }
}
// exact-tag poll for write-once hs words (poison 0xAA... can never match)
static __device__ __forceinline__ float poll_exact_sleep(const u64* p, int wanttag) {
    for (;;) {
        u64 wd = ld_tag(p);
        if ((int)(wd >> 32) == wanttag) return __uint_as_float((unsigned)wd);
        __builtin_amdgcn_s_sleep(8);
    }
}

// ---------------------------------------------------------------------------
// Concatenate the 4 encoder id arrays into one [2048] list
// ---------------------------------------------------------------------------
__global__ void prep_ids_kernel(const int* __restrict__ a, const int* __restrict__ b,
                                const int* __restrict__ c, const int* __restrict__ d,
                                int* __restrict__ out) {
    int t = blockIdx.x * blockDim.x + threadIdx.x;
    if (t >= 4 * TENC) return;
    int e = t >> 9, i = t & 511;
    const int* src = (e == 0) ? a : (e == 1) ? b : (e == 2) ? c : d;
    out[t] = src[i];
}

// ---------------------------------------------------------------------------
// Stable bucket-by-tag, sorted by step within each bucket (so head tiles
// become available progressively as the decoder advances). 1 block.
// ---------------------------------------------------------------------------
__global__ __launch_bounds__(256)
void bucket_kernel(const int* __restrict__ tags, int* __restrict__ lists,
                   int* __restrict__ counts) {
    __shared__ int segcnt[4][256];
    int tid = threadIdx.x;
    int s0 = tid * 8;
    int c0 = 0, c1 = 0, c2 = 0, c3 = 0;
    for (int i = 0; i < 8; i++) {
        int g = tags[s0 + i]; if (g < 0 || g > 3) g = 3;
        c0 += (g == 0); c1 += (g == 1); c2 += (g == 2); c3 += (g == 3);
    }
    segcnt[0][tid] = c0; segcnt[1][tid] = c1; segcnt[2][tid] = c2; segcnt[3][tid] = c3;
    __syncthreads();
    if (tid == 0) {
        int t0 = 0, t1 = 0, t2 = 0, t3 = 0;
        for (int t = 0; t < 256; t++) {
            int a;
            a = segcnt[0][t]; segcnt[0][t] = t0; t0 += a;
            a = segcnt[1][t]; segcnt[1][t] = t1; t1 += a;
            a = segcnt[2][t]; segcnt[2][t] = t2; t2 += a;
            a = segcnt[3][t]; segcnt[3][t] = t3; t3 += a;
        }
        counts[0] = t0; counts[1] = t1; counts[2] = t2; counts[3] = t3;
    }
    __syncthreads();
    int o0 = segcnt[0][tid], o1 = segcnt[1][tid], o2 = segcnt[2][tid], o3 = segcnt[3][tid];
    for (int i = 0; i < 8; i++) {
        int step = s0 + i;
        int g = tags[step]; if (g < 0 || g > 3) g = 3;
        int off = (g == 0) ? o0++ : (g == 1) ? o1++ : (g == 2) ? o2++ : o3++;
        lists[g * TDEC + off] = step;
    }
}

// ---------------------------------------------------------------------------
// Gathered GEMM for xg precompute: out[t][col] = emb[ids[t]][:] . W[col][:] + b
// ---------------------------------------------------------------------------
__global__ __launch_bounds__(256)
void gemm_gather_kernel(const float* __restrict__ A, const float* __restrict__ W,
                        const float* __restrict__ bias,
                        const int* __restrict__ aidx, int M, int N,
                        float* __restrict__ out) {
    int rb = blockIdx.y * BLK;
    int cb = blockIdx.x * BLK;
    if (rb >= M || cb >= N) return;

    int tid = threadIdx.x;
    int tx = tid & 15, ty = tid >> 4;

    __shared__ int ridx[BLK];
    if (tid < BLK) {
        int t = rb + tid;
        ridx[tid] = (t < M) ? aidx[t] : 0;
    }
    __syncthreads();

    __shared__ float As[BLK][PAD];
    __shared__ float Bs[BLK][PAD];
    float acc[4][4] = {{0.f}};

    for (int kc = 0; kc < HDIM; kc += KC) {
        for (int e = tid; e < BLK * KC; e += 256) {
            int r = e / KC, k = e - r * KC;
            float v = 0.f;
            if (rb + r < M) v = A[(size_t)ridx[r] * HDIM + kc + k];
            As[r][k] = v;
        }
        for (int e = tid; e < BLK * KC; e += 256) {
            int r = e / KC, k = e - r * KC;
            int col = cb + r;
            float v = 0.f;
            if (col < N) v = W[(size_t)col * HDIM + kc + k];
            Bs[r][k] = v;
        }
        __syncthreads();
        #pragma unroll 5
        for (int k = 0; k < KC; k++) {
            float a0 = As[ty * 4 + 0][k], a1 = As[ty * 4 + 1][k];
            float a2 = As[ty * 4 + 2][k], a3 = As[ty * 4 + 3][k];
            float b0 = Bs[tx * 4 + 0][k], b1 = Bs[tx * 4 + 1][k];
            float b2 = Bs[tx * 4 + 2][k], b3 = Bs[tx * 4 + 3][k];
            acc[0][0] += a0 * b0; acc[0][1] += a0 * b1; acc[0][2] += a0 * b2; acc[0][3] += a0 * b3;
            acc[1][0] += a1 * b0; acc[1][1] += a1 * b1; acc[1][2] += a1 * b2; acc[1][3] += a1 * b3;
            acc[2][0] += a2 * b0; acc[2][1] += a2 * b1; acc[2][2] += a2 * b2; acc[2][3] += a2 * b3;
            acc[3][0] += a3 * b0; acc[3][1] += a3 * b1; acc[3][2] += a3 * b2; acc[3][3] += a3 * b3;
        }
        __syncthreads();
    }

    #pragma unroll
    for (int i = 0; i < 4; i++) {
        int o = rb + ty * 4 + i;
        if (o >= M) continue;
        #pragma unroll
        for (int j = 0; j < 4; j++) {
            int col = cb + tx * 4 + j;
            if (col < N) out[(size_t)o * N + col] = acc[i][j] + bias[col];
        }
    }
}

// ---------------------------------------------------------------------------
// Head-GEMM worker: claims (level, bucket, col-tile) tiles from a global
// counter in availability order; polls hs tagged words (exact tag = step+2).
// Runs inside gru_rnn_kernel on WGs that have no (more) recurrence work.
// ---------------------------------------------------------------------------
__device__ void head_worker(float* smem, const u64* hs_tag,
                            const int* lists, const int* counts, int* tile_ctr,
                            const float* nW, const float* nb,
                            const float* vW, const float* vbs,
                            const float* pW, const float* pb,
                            const float* sW, const float* sb,
                            float* out) {
    const int tid = threadIdx.x;
    float* As = smem;                         // [64][PAD]
    float* Bs = smem + BLK * PAD;             // [64][PAD]
    int* steps_l = (int*)(smem + 2 * BLK * PAD);   // [64]
    int* tshare  = steps_l + BLK;

    int cnts[4] = {counts[0], counts[1], counts[2], counts[3]};
    int RT[4], Lmax = 0;
    for (int g = 0; g < 4; g++) {
        RT[g] = (cnts[g] + BLK - 1) / BLK;
        if (RT[g] > Lmax) Lmax = RT[g];
    }
    const int total = Lmax * TILES_PER_LVL;
    const int tx = tid & 15, ty = tid >> 4;

    for (;;) {
        __syncthreads();   // protect tshare/steps_l/As/Bs from previous tile
        if (tid == 0)
            *tshare = __hip_atomic_fetch_add(tile_ctr, 1, __ATOMIC_RELAXED, AGENT_SCOPE);
        __syncthreads();
        int t = *tshare;
        if (t >= total) break;

        int lvl = t / TILES_PER_LVL;
        int rem = t - lvl * TILES_PER_LVL;
        int g = rem / CT_ALL;
        int cb = (rem - g * CT_ALL) * BLK;
        if (lvl >= RT[g]) continue;

        int rb = lvl * BLK;
        int M = cnts[g];
        const float* Wg = (g == 0) ? nW : (g == 1) ? vW : (g == 2) ? pW : sW;
        const float* bg = (g == 0) ? nb : (g == 1) ? vbs : (g == 2) ? pb : sb;
        int Ngr        = (g == 0) ? NOUNC : (g == 1) ? VERBC : (g == 2) ? PRONC : VSZ;

        if (tid < BLK) steps_l[tid] = (rb + tid < M) ? lists[g * TDEC + rb + tid] : -1;
        __syncthreads();

        if (cb >= Ngr) {
            // pure zero-fill tile (padding region of masked heads)
            for (int e = tid; e < BLK * BLK; e += 256) {
                int i = e >> 6, j = e & 63;
                int st = steps_l[i]; int col = cb + j;
                if (st >= 0 && col < VSZ) out[(size_t)st * VSZ + col] = 0.f;
            }
            continue;
        }

        float acc[4][4] = {{0.f}};
        for (int kc = 0; kc < HDIM; kc += KC) {
            __syncthreads();
            for (int e = tid; e < BLK * KC; e += 256) {
                int r = e / KC, k = e - r * KC;
                int st = steps_l[r];
                float v = 0.f;
                if (st >= 0)
                    v = poll_exact_sleep(hs_tag + (size_t)st * HDIM + kc + k, st + 2);
                As[r * PAD + k] = v;
            }
            for (int e = tid; e < BLK * KC; e += 256) {
                int r = e / KC, k = e - r * KC;
                int col = cb + r;
                Bs[r * PAD + k] = (col < Ngr) ? Wg[(size_t)col * HDIM + kc + k] : 0.f;
            }
            __syncthreads();
            #pragma unroll 5
            for (int k = 0; k < KC; k++) {
                float a0 = As[(ty * 4 + 0) * PAD + k], a1 = As[(ty * 4 + 1) * PAD + k];
                float a2 = As[(ty * 4 + 2) * PAD + k], a3 = As[(ty * 4 + 3) * PAD + k];
                float b0 = Bs[(tx * 4 + 0) * PAD + k], b1 = Bs[(tx * 4 + 1) * PAD + k];
                float b2 = Bs[(tx * 4 + 2) * PAD + k], b3 = Bs[(tx * 4 + 3) * PAD + k];
                acc[0][0] += a0 * b0; acc[0][1] += a0 * b1; acc[0][2] += a0 * b2; acc[0][3] += a0 * b3;
                acc[1][0] += a1 * b0; acc[1][1] += a1 * b1; acc[1][2] += a1 * b2; acc[1][3] += a1 * b3;
                acc[2][0] += a2 * b0; acc[2][1] += a2 * b1; acc[2][2] += a2 * b2; acc[2][3] += a2 * b3;
                acc[3][0] += a3 * b0; acc[3][1] += a3 * b1; acc[3][2] += a3 * b2; acc[3][3] += a3 * b3;
            }
        }
        #pragma unroll
        for (int i = 0; i < 4; i++) {
            int st = steps_l[ty * 4 + i];
            if (st < 0) continue;
            #pragma unroll
            for (int j = 0; j < 4; j++) {
                int col = cb + tx * 4 + j;
                if (col < VSZ)
                    out[(size_t)st * VSZ + col] = (col < Ngr) ? acc[i][j] + bg[col] : 0.f;
            }
        }
    }
}

// ---------------------------------------------------------------------------
// Persistent GRU recurrence with tagged-word handoff + fused head GEMMs.
// hbuf: [lane][parity][HDIM] u64 words (ver<<32 | f32). Encoders: step s
// consumes ver s, publishes s+1 (h0 = ver 0 = memset zeros). Decoder:
// versions +1 (hidden = ver 1); publishes h after step s as ver s+2 and
// also writes hs_tag[s][:] with tag s+2 (write-once, exact-match polled).
// WGs with no recurrence work (lanes 5-7) and WGs that finish their
// recurrence become head-GEMM workers.
// ---------------------------------------------------------------------------
__global__ __launch_bounds__(256)
void gru_rnn_kernel(const float* __restrict__ enc_xg, const float* __restrict__ dec_xg,
                    const float* __restrict__ encWhh, const float* __restrict__ encbhh,
                    const float* __restrict__ decWhh, const float* __restrict__ decbhh,
                    const float* __restrict__ stateW, const float* __restrict__ stateb,
                    u64* hs_tag, u64* hbuf,
                    const int* __restrict__ lists, const int* __restrict__ counts,
                    int* tile_ctr,
                    const float* __restrict__ hnW, const float* __restrict__ hnb,
                    const float* __restrict__ hvW, const float* __restrict__ hvb,
                    const float* __restrict__ hpW, const float* __restrict__ hpb,
                    const float* __restrict__ hsW, const float* __restrict__ hsb,
                    float* __restrict__ out) {
    __shared__ float smem[19680];   // 78.7 KB, carved per phase
    int bid = blockIdx.x;
    int lane = bid & 7;
    int w = bid >> 3;

    if (lane >= LANES || w >= KWG) {
        // no recurrence role: straight to head work
        head_worker(smem, hs_tag, lists, counts, tile_ctr,
                    hnW, hnb, hvW, hvb, hpW, hpb, hsW, hsb, out);
        return;
    }

    const bool isdec = (lane == 4);
    const float* Whh = isdec ? decWhh : encWhh;
    const float* bhh = isdec ? decbhh : encbhh;
    const float* xg  = isdec ? dec_xg : (enc_xg + (size_t)lane * TENC * G3);
    const int T     = isdec ? TDEC : TENC;
    const int vbase = isdec ? 1 : 0; // step s consumes ver s+vbase, publishes s+vbase+1
    u64* myh = hbuf + (size_t)lane * 2 * HDIM;

    const int tid = threadIdx.x;
    const int lr  = tid >> 2;        // local row 0..63 (valid < ROWSW)
    const int c   = tid & 3;         // K-chunk 0..3

    float* whh_lds = smem;                    // [ROWSW][WLD] = 18060
    float* h_lds   = smem + 18060;            // [4*76] chunk-padded = 304
    float* gh_lds  = smem + 18364;            // [ROWSW]
    float* bhh_lds = smem + 18424;            // [ROWSW]
    float* henc    = smem + 18484;            // [4][HDIM] decoder only

    // stage Whh slice: local row r -> global row (r/20)*300 + w*20 + r%20
    for (int e = tid; e < ROWSW * HDIM; e += 256) {
        int r = e / HDIM, col = e - r * HDIM;
        int grow = (r / SLICE) * HDIM + w * SLICE + (r % SLICE);
        whh_lds[r * WLD + col] = Whh[(size_t)grow * HDIM + col];
    }
    if (tid < ROWSW)
        bhh_lds[tid] = bhh[(tid / SLICE) * HDIM + w * SLICE + (tid % SLICE)];

    if (isdec) {
        // stage encoder finals (ver TENC, parity 0)
        for (int e = tid; e < 4 * HDIM; e += 256) {
            int l2 = e / HDIM, i = e - l2 * HDIM;
            henc[l2 * HDIM + i] = poll_word_sleep(hbuf + (size_t)l2 * 2 * HDIM + i, TENC);
        }
        __syncthreads();
        // hidden = concat(verb,pron,noun,sen) @ state_W.T + state_b  (ver 1)
        if (tid < 4 * SLICE) {
            int jj = tid >> 2, c2 = tid & 3;
            const float* wrow = stateW + (size_t)(w * SLICE + jj) * (4 * HDIM) + c2 * HDIM;
            float a = 0.f;
            for (int i = 0; i < HDIM; i++) a += wrow[i] * henc[c2 * HDIM + i];
            a += __shfl_xor(a, 1);
            a += __shfl_xor(a, 2);
            if (c2 == 0)
                st_tag(&myh[1 * HDIM + w * SLICE + jj], a + stateb[w * SLICE + jj], 1);
        }
    }
    __syncthreads();   // whh_lds/bhh_lds ready

    for (int s = 0; s < T; ++s) {
        const int want = s + vbase;
        // 1. poll+stage h (ver want) — dual CONCURRENT poll so the slowest
        //    thread pays ~1 coherent round trip, not 2 serial ones
        {
            const u64* src = myh + (size_t)(want & 1) * HDIM;
            if (tid < HDIM) {
                int t2 = tid + 256;
                if (t2 < HDIM) {
                    u64 w1, w2; float v1 = 0.f, v2 = 0.f;
                    bool d1 = false, d2 = false;
                    for (;;) {
                        if (!d1) { w1 = ld_tag(&src[tid]);
                                   if ((int)(w1 >> 32) >= want) { v1 = __uint_as_float((unsigned)w1); d1 = true; } }
                        if (!d2) { w2 = ld_tag(&src[t2]);
                                   if ((int)(w2 >> 32) >= want) { v2 = __uint_as_float((unsigned)w2); d2 = true; } }
                        if (d1 && d2) break;
                    }
                    h_lds[(tid / 75) * 76 + (tid % 75)] = v1;
                    h_lds[(t2 / 75) * 76 + (t2 % 75)] = v2;
                } else {
                    h_lds[(tid / 75) * 76 + (tid % 75)] = poll_word(&src[tid], want);
                }
            }
        }
        __syncthreads();
        // 2. partial matvec: gh[lr] over K-chunk c
        if (lr < ROWSW) {
            const float* wr = &whh_lds[lr * WLD + c * CHUNK];
            const float* hc = &h_lds[c * 76];
            float a0 = 0.f, a1 = 0.f, a2 = 0.f, a3 = 0.f;
            #pragma unroll
            for (int i = 0; i < 72; i += 4) {
                a0 += wr[i + 0] * hc[i + 0];
                a1 += wr[i + 1] * hc[i + 1];
                a2 += wr[i + 2] * hc[i + 2];
                a3 += wr[i + 3] * hc[i + 3];
            }
            a0 += wr[72] * hc[72];
            a1 += wr[73] * hc[73];
            a2 += wr[74] * hc[74];
            float acc = (a0 + a1) + (a2 + a3);
            acc += __shfl_xor(acc, 1);
            acc += __shfl_xor(acc, 2);
            if (c == 0) gh_lds[lr] = acc;
        }
        __syncthreads();
        // 3. gates + publish (20 lanes; full-precision expf/tanhf)
        if (tid < SLICE) {
            int jj = tid;
            float ghr = gh_lds[jj]             + bhh_lds[jj];
            float ghz = gh_lds[SLICE + jj]     + bhh_lds[SLICE + jj];
            float ghn = gh_lds[2 * SLICE + jj] + bhh_lds[2 * SLICE + jj];
            const float* xrow = xg + (size_t)s * G3 + w * SLICE + jj;
            float xr = xrow[0], xz = xrow[HDIM], xn = xrow[2 * HDIM];
            float r = 1.f / (1.f + expf(-(xr + ghr)));
            float z = 1.f / (1.f + expf(-(xz + ghz)));
            float n  = tanhf(xn + r * ghn);
            int gj = w * SLICE + jj;
            float hold = h_lds[(gj / 75) * 76 + (gj % 75)];
            float hnew = (1.f - z) * n + z * hold;
            st_tag(&myh[(size_t)((want + 1) & 1) * HDIM + gj], hnew, want + 1);
            if (isdec) st_tag(&hs_tag[(size_t)s * HDIM + gj], hnew, want + 1);
        }
        __syncthreads();   // protect h_lds/gh_lds before next stage
    }

    // recurrence done for this WG -> join the head-GEMM worker pool
    __syncthreads();
    head_worker(smem, hs_tag, lists, counts, tile_ctr,
                hnW, hnb, hvW, hvb, hpW, hpb, hsW, hsb, out);
}

// ---------------------------------------------------------------------------
// Host launch
// ---------------------------------------------------------------------------
extern "C" void kernel_launch(void* const* d_in, const int* in_sizes, int n_in,
                              void* d_out, int out_size, void* d_ws, size_t ws_size,
                              hipStream_t stream) {
    const int* verb_in = (const int*)d_in[0];
    const int* pron_in = (const int*)d_in[1];
    const int* noun_in = (const int*)d_in[2];
    const int* sen_in  = (const int*)d_in[3];
    const int* tgt_in  = (const int*)d_in[4];
    const int* tgt_tag = (const int*)d_in[5];
    const float* emb      = (const float*)d_in[6];
    const float* enc_Wih  = (const float*)d_in[7];
    const float* enc_Whh  = (const float*)d_in[8];
    const float* enc_bih  = (const float*)d_in[9];
    const float* enc_bhh  = (const float*)d_in[10];
    const float* dec_Wih  = (const float*)d_in[11];
    const float* dec_Whh  = (const float*)d_in[12];
    const float* dec_bih  = (const float*)d_in[13];
    const float* dec_bhh  = (const float*)d_in[14];
    const float* state_W  = (const float*)d_in[15];
    const float* state_b  = (const float*)d_in[16];
    const float* noun_W   = (const float*)d_in[17];
    const float* noun_b   = (const float*)d_in[18];
    const float* verb_W   = (const float*)d_in[19];
    const float* verb_b   = (const float*)d_in[20];
    const float* pron_W   = (const float*)d_in[21];
    const float* pron_b   = (const float*)d_in[22];
    const float* sen_W    = (const float*)d_in[23];
    const float* sen_b    = (const float*)d_in[24];

    float* out = (float*)d_out;
    char* ws = (char*)d_ws;

    // ws layout (bytes), total ~19.73 MB
    float* enc_xg  = (float*)(ws + 0);                       // 4*512*900 f = 7372800
    float* dec_xg  = (float*)(ws + 7372800);                 // 2048*900 f  = 7372800
    u64*   hs_tag  = (u64*)  (ws + 14745600);                // 2048*300 u64 = 4915200
    int*   enc_ids = (int*)  (ws + 19660800);                // 8192
    int*   lists   = (int*)  (ws + 19668992);                // 4*2048 i = 32768
    int*   counts  = (int*)  (ws + 19701760);                // 64
    u64*   hbuf    = (u64*)  (ws + 19701824);                // 5*2*300 u64 = 24000
    int*   tile_ctr= (int*)  (ws + 19725824);                // 64
    // hs_tag is NOT zeroed: poison 0xAAAAAAAA can never equal tag step+2.

    // zero hbuf (ver 0 == encoder h0 == 0.0f) + tile counter in one memset
    hipMemsetAsync(ws + 19701824, 0, 24000 + 64, stream);

    prep_ids_kernel<<<8, 256, 0, stream>>>(verb_in, pron_in, noun_in, sen_in, enc_ids);

    // xg = emb[ids] @ Wih.T + bih   (enc: 4x512 rows; dec: 2048 rows)
    gemm_gather_kernel<<<dim3(15, 32), 256, 0, stream>>>(
        emb, enc_Wih, enc_bih, enc_ids, 4 * TENC, G3, enc_xg);
    gemm_gather_kernel<<<dim3(15, 32), 256, 0, stream>>>(
        emb, dec_Wih, dec_bih, tgt_in, TDEC, G3, dec_xg);

    bucket_kernel<<<1, 256, 0, stream>>>(tgt_tag, lists, counts);

    gru_rnn_kernel<<<8 * KWG, 256, 0, stream>>>(
        enc_xg, dec_xg, enc_Whh, enc_bhh, dec_Whh, dec_bhh,
        state_W, state_b, hs_tag, hbuf, lists, counts, tile_ctr,
        noun_W, noun_b, verb_W, verb_b, pron_W, pron_b, sen_W, sen_b, out);
}

// Round 8
// 5454.420 us; speedup vs baseline: 3.2375x; 1.1911x over previous
//
#include <hip/hip_runtime.h>
#include <math.h>

// Problem constants
#define HDIM   300
#define G3     900          // 3*H
#define VSZ    19495
#define NOUNC  10000
#define PRONC  82
#define VERBC  6555
#define TENC   512
#define TDEC   2048

// Recurrence lane geometry
#define LANES  5            // 4 encoders + 1 decoder
#define KWG    15           // workgroups per lane
#define SLICE  20           // h outputs per WG (KWG*SLICE == HDIM)
#define ROWSW  60           // Whh rows per WG (3 gates * SLICE)
#define CHUNK  75           // K elements per thread (4 threads per row)
#define WROW   304          // LDS row stride for Whh slice (4 chunks x 76)
#define CPAD   76           // chunk stride (75 data + 1 pad), 76*4B=304B 16B-aligned

// GEMM tile
#define BLK 64
#define KC  75
#define PAD 77              // 77 mod 32 = 13 -> ~2-way banks

// Head tile enumeration: 305 col-tiles (ceil(VSZ/64)) x 4 buckets per level
#define CT_ALL 305
#define TILES_PER_LVL (4 * CT_ALL)

#define AGENT_SCOPE __HIP_MEMORY_SCOPE_AGENT
typedef unsigned long long u64;

// Tagged-word handoff: one 8B word = (version<<32 | float bits). Relaxed
// agent-scope atomics only — no acquire/release (those cost whole-L2
// inv/writeback per op on multi-XCD gfx950). Tag travels atomically with
// the value, so no ordering/fences are needed anywhere in the hot loop.
static __device__ __forceinline__ u64 ld_tag(const u64* p) {
    return __hip_atomic_load((u64*)p, __ATOMIC_RELAXED, AGENT_SCOPE);
}
static __device__ __forceinline__ void st_tag(u64* p, float v, int ver) {
    u64 wd = ((u64)(unsigned)ver << 32) | (u64)__float_as_uint(v);
    __hip_atomic_store(p, wd, __ATOMIC_RELAXED, AGENT_SCOPE);
}
static __device__ __forceinline__ float poll_word(const u64* p, int want) {
    for (;;) {
        u64 wd = ld_tag(p);
        if ((int)(wd >> 32) >= want) return __uint_as_float((unsigned)wd);
    }
}
static __device__ __forceinline__ float poll_word_sleep(const u64* p, int want) {
    for (;;) {
        u64 wd = ld_tag(p);
        if ((int)(wd >> 32) >= want) return __uint_as_float((unsigned)wd);
        __builtin_amdgcn_s_sleep(16);
    }
}
// exact-tag poll for write-once hs words (poison 0xAA... can never match)
static __device__ __forceinline__ float poll_exact_sleep(const u64* p, int wanttag) {
    for (;;) {
        u64 wd = ld_tag(p);
        if ((int)(wd >> 32) == wanttag) return __uint_as_float((unsigned)wd);
        __builtin_amdgcn_s_sleep(8);
    }
}

// ---------------------------------------------------------------------------
// Concatenate the 4 encoder id arrays into one [2048] list
// ---------------------------------------------------------------------------
__global__ void prep_ids_kernel(const int* __restrict__ a, const int* __restrict__ b,
                                const int* __restrict__ c, const int* __restrict__ d,
                                int* __restrict__ out) {
    int t = blockIdx.x * blockDim.x + threadIdx.x;
    if (t >= 4 * TENC) return;
    int e = t >> 9, i = t & 511;
    const int* src = (e == 0) ? a : (e == 1) ? b : (e == 2) ? c : d;
    out[t] = src[i];
}

// ---------------------------------------------------------------------------
// Stable bucket-by-tag, sorted by step within each bucket (so head tiles
// become available progressively as the decoder advances). 1 block.
// ---------------------------------------------------------------------------
__global__ __launch_bounds__(256)
void bucket_kernel(const int* __restrict__ tags, int* __restrict__ lists,
                   int* __restrict__ counts) {
    __shared__ int segcnt[4][256];
    int tid = threadIdx.x;
    int s0 = tid * 8;
    int c0 = 0, c1 = 0, c2 = 0, c3 = 0;
    for (int i = 0; i < 8; i++) {
        int g = tags[s0 + i]; if (g < 0 || g > 3) g = 3;
        c0 += (g == 0); c1 += (g == 1); c2 += (g == 2); c3 += (g == 3);
    }
    segcnt[0][tid] = c0; segcnt[1][tid] = c1; segcnt[2][tid] = c2; segcnt[3][tid] = c3;
    __syncthreads();
    if (tid == 0) {
        int t0 = 0, t1 = 0, t2 = 0, t3 = 0;
        for (int t = 0; t < 256; t++) {
            int a;
            a = segcnt[0][t]; segcnt[0][t] = t0; t0 += a;
            a = segcnt[1][t]; segcnt[1][t] = t1; t1 += a;
            a = segcnt[2][t]; segcnt[2][t] = t2; t2 += a;
            a = segcnt[3][t]; segcnt[3][t] = t3; t3 += a;
        }
        counts[0] = t0; counts[1] = t1; counts[2] = t2; counts[3] = t3;
    }
    __syncthreads();
    int o0 = segcnt[0][tid], o1 = segcnt[1][tid], o2 = segcnt[2][tid], o3 = segcnt[3][tid];
    for (int i = 0; i < 8; i++) {
        int step = s0 + i;
        int g = tags[step]; if (g < 0 || g > 3) g = 3;
        int off = (g == 0) ? o0++ : (g == 1) ? o1++ : (g == 2) ? o2++ : o3++;
        lists[g * TDEC + off] = step;
    }
}

// ---------------------------------------------------------------------------
// Gathered GEMM for xg precompute: out[t][col] = emb[ids[t]][:] . W[col][:] + b
// ---------------------------------------------------------------------------
__global__ __launch_bounds__(256)
void gemm_gather_kernel(const float* __restrict__ A, const float* __restrict__ W,
                        const float* __restrict__ bias,
                        const int* __restrict__ aidx, int M, int N,
                        float* __restrict__ out) {
    int rb = blockIdx.y * BLK;
    int cb = blockIdx.x * BLK;
    if (rb >= M || cb >= N) return;

    int tid = threadIdx.x;
    int tx = tid & 15, ty = tid >> 4;

    __shared__ int ridx[BLK];
    if (tid < BLK) {
        int t = rb + tid;
        ridx[tid] = (t < M) ? aidx[t] : 0;
    }
    __syncthreads();

    __shared__ float As[BLK][PAD];
    __shared__ float Bs[BLK][PAD];
    float acc[4][4] = {{0.f}};

    for (int kc = 0; kc < HDIM; kc += KC) {
        for (int e = tid; e < BLK * KC; e += 256) {
            int r = e / KC, k = e - r * KC;
            float v = 0.f;
            if (rb + r < M) v = A[(size_t)ridx[r] * HDIM + kc + k];
            As[r][k] = v;
        }
        for (int e = tid; e < BLK * KC; e += 256) {
            int r = e / KC, k = e - r * KC;
            int col = cb + r;
            float v = 0.f;
            if (col < N) v = W[(size_t)col * HDIM + kc + k];
            Bs[r][k] = v;
        }
        __syncthreads();
        #pragma unroll 5
        for (int k = 0; k < KC; k++) {
            float a0 = As[ty * 4 + 0][k], a1 = As[ty * 4 + 1][k];
            float a2 = As[ty * 4 + 2][k], a3 = As[ty * 4 + 3][k];
            float b0 = Bs[tx * 4 + 0][k], b1 = Bs[tx * 4 + 1][k];
            float b2 = Bs[tx * 4 + 2][k], b3 = Bs[tx * 4 + 3][k];
            acc[0][0] += a0 * b0; acc[0][1] += a0 * b1; acc[0][2] += a0 * b2; acc[0][3] += a0 * b3;
            acc[1][0] += a1 * b0; acc[1][1] += a1 * b1; acc[1][2] += a1 * b2; acc[1][3] += a1 * b3;
            acc[2][0] += a2 * b0; acc[2][1] += a2 * b1; acc[2][2] += a2 * b2; acc[2][3] += a2 * b3;
            acc[3][0] += a3 * b0; acc[3][1] += a3 * b1; acc[3][2] += a3 * b2; acc[3][3] += a3 * b3;
        }
        __syncthreads();
    }

    #pragma unroll
    for (int i = 0; i < 4; i++) {
        int o = rb + ty * 4 + i;
        if (o >= M) continue;
        #pragma unroll
        for (int j = 0; j < 4; j++) {
            int col = cb + tx * 4 + j;
            if (col < N) out[(size_t)o * N + col] = acc[i][j] + bias[col];
        }
    }
}

// ---------------------------------------------------------------------------
// Head-GEMM worker: claims (level, bucket, col-tile) tiles from a global
// counter in availability order; polls hs tagged words (exact tag = step+2).
// Runs inside gru_rnn_kernel on WGs that have no (more) recurrence work.
// ---------------------------------------------------------------------------
__device__ void head_worker(float* smem, const u64* hs_tag,
                            const int* lists, const int* counts, int* tile_ctr,
                            const float* nW, const float* nb,
                            const float* vW, const float* vbs,
                            const float* pW, const float* pb,
                            const float* sW, const float* sb,
                            float* out) {
    const int tid = threadIdx.x;
    float* As = smem;                         // [64][PAD]
    float* Bs = smem + BLK * PAD;             // [64][PAD]
    int* steps_l = (int*)(smem + 2 * BLK * PAD);   // [64]
    int* tshare  = steps_l + BLK;

    int cnts[4] = {counts[0], counts[1], counts[2], counts[3]};
    int RT[4], Lmax = 0;
    for (int g = 0; g < 4; g++) {
        RT[g] = (cnts[g] + BLK - 1) / BLK;
        if (RT[g] > Lmax) Lmax = RT[g];
    }
    const int total = Lmax * TILES_PER_LVL;
    const int tx = tid & 15, ty = tid >> 4;

    for (;;) {
        __syncthreads();   // protect tshare/steps_l/As/Bs from previous tile
        if (tid == 0)
            *tshare = __hip_atomic_fetch_add(tile_ctr, 1, __ATOMIC_RELAXED, AGENT_SCOPE);
        __syncthreads();
        int t = *tshare;
        if (t >= total) break;

        int lvl = t / TILES_PER_LVL;
        int rem = t - lvl * TILES_PER_LVL;
        int g = rem / CT_ALL;
        int cb = (rem - g * CT_ALL) * BLK;
        if (lvl >= RT[g]) continue;

        int rb = lvl * BLK;
        int M = cnts[g];
        const float* Wg = (g == 0) ? nW : (g == 1) ? vW : (g == 2) ? pW : sW;
        const float* bg = (g == 0) ? nb : (g == 1) ? vbs : (g == 2) ? pb : sb;
        int Ngr        = (g == 0) ? NOUNC : (g == 1) ? VERBC : (g == 2) ? PRONC : VSZ;

        if (tid < BLK) steps_l[tid] = (rb + tid < M) ? lists[g * TDEC + rb + tid] : -1;
        __syncthreads();

        if (cb >= Ngr) {
            // pure zero-fill tile (padding region of masked heads)
            for (int e = tid; e < BLK * BLK; e += 256) {
                int i = e >> 6, j = e & 63;
                int st = steps_l[i]; int col = cb + j;
                if (st >= 0 && col < VSZ) out[(size_t)st * VSZ + col] = 0.f;
            }
            continue;
        }

        float acc[4][4] = {{0.f}};
        for (int kc = 0; kc < HDIM; kc += KC) {
            __syncthreads();
            for (int e = tid; e < BLK * KC; e += 256) {
                int r = e / KC, k = e - r * KC;
                int st = steps_l[r];
                float v = 0.f;
                if (st >= 0)
                    v = poll_exact_sleep(hs_tag + (size_t)st * HDIM + kc + k, st + 2);
                As[r * PAD + k] = v;
            }
            for (int e = tid; e < BLK * KC; e += 256) {
                int r = e / KC, k = e - r * KC;
                int col = cb + r;
                Bs[r * PAD + k] = (col < Ngr) ? Wg[(size_t)col * HDIM + kc + k] : 0.f;
            }
            __syncthreads();
            #pragma unroll 5
            for (int k = 0; k < KC; k++) {
                float a0 = As[(ty * 4 + 0) * PAD + k], a1 = As[(ty * 4 + 1) * PAD + k];
                float a2 = As[(ty * 4 + 2) * PAD + k], a3 = As[(ty * 4 + 3) * PAD + k];
                float b0 = Bs[(tx * 4 + 0) * PAD + k], b1 = Bs[(tx * 4 + 1) * PAD + k];
                float b2 = Bs[(tx * 4 + 2) * PAD + k], b3 = Bs[(tx * 4 + 3) * PAD + k];
                acc[0][0] += a0 * b0; acc[0][1] += a0 * b1; acc[0][2] += a0 * b2; acc[0][3] += a0 * b3;
                acc[1][0] += a1 * b0; acc[1][1] += a1 * b1; acc[1][2] += a1 * b2; acc[1][3] += a1 * b3;
                acc[2][0] += a2 * b0; acc[2][1] += a2 * b1; acc[2][2] += a2 * b2; acc[2][3] += a2 * b3;
                acc[3][0] += a3 * b0; acc[3][1] += a3 * b1; acc[3][2] += a3 * b2; acc[3][3] += a3 * b3;
            }
        }
        #pragma unroll
        for (int i = 0; i < 4; i++) {
            int st = steps_l[ty * 4 + i];
            if (st < 0) continue;
            #pragma unroll
            for (int j = 0; j < 4; j++) {
                int col = cb + tx * 4 + j;
                if (col < VSZ)
                    out[(size_t)st * VSZ + col] = (col < Ngr) ? acc[i][j] + bg[col] : 0.f;
            }
        }
    }
}

// ---------------------------------------------------------------------------
// Persistent GRU recurrence with tagged-word handoff + fused head GEMMs.
// hbuf: [lane][parity][HDIM] u64 words (ver<<32 | f32). Encoders: step s
// consumes ver s, publishes s+1 (h0 = ver 0 = memset zeros). Decoder:
// versions +1 (hidden = ver 1); publishes h after step s as ver s+2 and
// also writes hs_tag[s][:] with tag s+2 (write-once, exact-match polled).
// This revision: float4 LDS matvec (aligned 76-float chunks), 2 barriers
// per step (register-held h_old removes the post-gates barrier), xg
// prefetch at step start. FLOP order identical to r7 (absmax-preserving).
// ---------------------------------------------------------------------------
__global__ __launch_bounds__(256)
void gru_rnn_kernel(const float* __restrict__ enc_xg, const float* __restrict__ dec_xg,
                    const float* __restrict__ encWhh, const float* __restrict__ encbhh,
                    const float* __restrict__ decWhh, const float* __restrict__ decbhh,
                    const float* __restrict__ stateW, const float* __restrict__ stateb,
                    u64* hs_tag, u64* hbuf,
                    const int* __restrict__ lists, const int* __restrict__ counts,
                    int* tile_ctr,
                    const float* __restrict__ hnW, const float* __restrict__ hnb,
                    const float* __restrict__ hvW, const float* __restrict__ hvb,
                    const float* __restrict__ hpW, const float* __restrict__ hpb,
                    const float* __restrict__ hsW, const float* __restrict__ hsb,
                    float* __restrict__ out) {
    __shared__ float smem[19880];   // 79.5 KB, carved per phase
    int bid = blockIdx.x;
    int lane = bid & 7;
    int w = bid >> 3;

    if (lane >= LANES || w >= KWG) {
        // no recurrence role: straight to head work
        head_worker(smem, hs_tag, lists, counts, tile_ctr,
                    hnW, hnb, hvW, hvb, hpW, hpb, hsW, hsb, out);
        return;
    }

    const bool isdec = (lane == 4);
    const float* Whh = isdec ? decWhh : encWhh;
    const float* bhh = isdec ? decbhh : encbhh;
    const float* xg  = isdec ? dec_xg : (enc_xg + (size_t)lane * TENC * G3);
    const int T     = isdec ? TDEC : TENC;
    const int vbase = isdec ? 1 : 0; // step s consumes ver s+vbase, publishes s+vbase+1
    u64* myh = hbuf + (size_t)lane * 2 * HDIM;

    const int tid = threadIdx.x;
    const int lr  = tid >> 2;        // local row 0..63 (valid < ROWSW)
    const int c   = tid & 3;         // K-chunk 0..3

    float* whh_lds = smem;                    // [ROWSW][WROW] = 18240 (16B-aligned rows)
    float* h_lds   = smem + 18240;            // [4][CPAD] = 304 (16B-aligned chunks)
    float* gh_lds  = smem + 18544;            // [ROWSW]
    float* bhh_lds = smem + 18604;            // [ROWSW]
    float* henc    = smem + 18664;            // [4][HDIM] decoder only (ends 19864)

    // stage Whh slice: global row (r/20)*300 + w*20 + r%20, element k ->
    // LDS [r][ (k/75)*76 + k%75 ]  (chunk-aligned for float4 reads)
    for (int e = tid; e < ROWSW * HDIM; e += 256) {
        int r = e / HDIM, k = e - r * HDIM;
        int grow = (r / SLICE) * HDIM + w * SLICE + (r % SLICE);
        whh_lds[r * WROW + (k / CHUNK) * CPAD + (k % CHUNK)] = Whh[(size_t)grow * HDIM + k];
    }
    if (tid < ROWSW)
        bhh_lds[tid] = bhh[(tid / SLICE) * HDIM + w * SLICE + (tid % SLICE)];

    float h_old = 0.f;               // this thread's own h value (tid < SLICE)
    const int gj = w * SLICE + tid;  // valid when tid < SLICE

    if (isdec) {
        // stage encoder finals (ver TENC, parity 0)
        for (int e = tid; e < 4 * HDIM; e += 256) {
            int l2 = e / HDIM, i = e - l2 * HDIM;
            henc[l2 * HDIM + i] = poll_word_sleep(hbuf + (size_t)l2 * 2 * HDIM + i, TENC);
        }
        __syncthreads();
        // hidden = concat(verb,pron,noun,sen) @ state_W.T + state_b  (ver 1)
        if (tid < 4 * SLICE) {
            int jj = tid >> 2, c2 = tid & 3;
            const float* wrow = stateW + (size_t)(w * SLICE + jj) * (4 * HDIM) + c2 * HDIM;
            float a = 0.f;
            for (int i = 0; i < HDIM; i++) a += wrow[i] * henc[c2 * HDIM + i];
            a += __shfl_xor(a, 1);
            a += __shfl_xor(a, 2);
            if (c2 == 0)
                st_tag(&myh[1 * HDIM + w * SLICE + jj], a + stateb[w * SLICE + jj], 1);
        }
    }
    __syncthreads();   // whh_lds/bhh_lds (and hidden publish) ready

    // seed register h_old: encoders start at h0=0; decoder reads back its own
    // published hidden word (same-address coherence after barrier)
    if (isdec && tid < SLICE)
        h_old = poll_word(&myh[1 * HDIM + gj], 1);

    for (int s = 0; s < T; ++s) {
        const int want = s + vbase;
        // xg prefetch: issue global loads now; consumed in gates after 2
        // barriers -> latency fully hidden
        float xr = 0.f, xz = 0.f, xn = 0.f;
        if (tid < SLICE) {
            const float* xrow = xg + (size_t)s * G3 + gj;
            xr = xrow[0]; xz = xrow[HDIM]; xn = xrow[2 * HDIM];
        }
        // 1. poll+stage h (ver want) — dual CONCURRENT poll
        {
            const u64* src = myh + (size_t)(want & 1) * HDIM;
            if (tid < HDIM) {
                int t2 = tid + 256;
                if (t2 < HDIM) {
                    u64 w1, w2; float v1 = 0.f, v2 = 0.f;
                    bool d1 = false, d2 = false;
                    for (;;) {
                        if (!d1) { w1 = ld_tag(&src[tid]);
                                   if ((int)(w1 >> 32) >= want) { v1 = __uint_as_float((unsigned)w1); d1 = true; } }
                        if (!d2) { w2 = ld_tag(&src[t2]);
                                   if ((int)(w2 >> 32) >= want) { v2 = __uint_as_float((unsigned)w2); d2 = true; } }
                        if (d1 && d2) break;
                    }
                    h_lds[(tid / CHUNK) * CPAD + (tid % CHUNK)] = v1;
                    h_lds[(t2 / CHUNK) * CPAD + (t2 % CHUNK)] = v2;
                } else {
                    h_lds[(tid / CHUNK) * CPAD + (tid % CHUNK)] = poll_word(&src[tid], want);
                }
            }
        }
        __syncthreads();   // barrier 1: h_lds staged
        // 2. partial matvec via float4 LDS reads (identical FLOP order:
        //    x->a0, y->a1, z->a2, w->a3, i stepping by 4)
        if (lr < ROWSW) {
            const float4* wr4 = (const float4*)&whh_lds[lr * WROW + c * CPAD];
            const float4* hc4 = (const float4*)&h_lds[c * CPAD];
            float a0 = 0.f, a1 = 0.f, a2 = 0.f, a3 = 0.f;
            #pragma unroll
            for (int i4 = 0; i4 < 18; i4++) {
                float4 wv = wr4[i4], hv = hc4[i4];
                a0 += wv.x * hv.x;
                a1 += wv.y * hv.y;
                a2 += wv.z * hv.z;
                a3 += wv.w * hv.w;
            }
            const float* wrs = &whh_lds[lr * WROW + c * CPAD];
            const float* hcs = &h_lds[c * CPAD];
            a0 += wrs[72] * hcs[72];
            a1 += wrs[73] * hcs[73];
            a2 += wrs[74] * hcs[74];
            float acc = (a0 + a1) + (a2 + a3);
            acc += __shfl_xor(acc, 1);
            acc += __shfl_xor(acc, 2);
            if (c == 0) gh_lds[lr] = acc;
        }
        __syncthreads();   // barrier 2: gh_lds ready
        // 3. gates + publish (20 lanes; full-precision expf/tanhf). h_old is
        //    register-held -> no post-gates barrier needed (gates finish
        //    before next barrier 1 admits the gh-writing matvec; staging
        //    only touches h_lds, which gates no longer read).
        if (tid < SLICE) {
            float ghr = gh_lds[tid]             + bhh_lds[tid];
            float ghz = gh_lds[SLICE + tid]     + bhh_lds[SLICE + tid];
            float ghn = gh_lds[2 * SLICE + tid] + bhh_lds[2 * SLICE + tid];
            float r = 1.f / (1.f + expf(-(xr + ghr)));
            float z = 1.f / (1.f + expf(-(xz + ghz)));
            float n  = tanhf(xn + r * ghn);
            float hnew = (1.f - z) * n + z * h_old;
            h_old = hnew;
            st_tag(&myh[(size_t)((want + 1) & 1) * HDIM + gj], hnew, want + 1);
            if (isdec) st_tag(&hs_tag[(size_t)s * HDIM + gj], hnew, want + 1);
        }
    }

    // recurrence done for this WG -> join the head-GEMM worker pool
    __syncthreads();
    head_worker(smem, hs_tag, lists, counts, tile_ctr,
                hnW, hnb, hvW, hvb, hpW, hpb, hsW, hsb, out);
}

// ---------------------------------------------------------------------------
// Host launch
// ---------------------------------------------------------------------------
extern "C" void kernel_launch(void* const* d_in, const int* in_sizes, int n_in,
                              void* d_out, int out_size, void* d_ws, size_t ws_size,
                              hipStream_t stream) {
    const int* verb_in = (const int*)d_in[0];
    const int* pron_in = (const int*)d_in[1];
    const int* noun_in = (const int*)d_in[2];
    const int* sen_in  = (const int*)d_in[3];
    const int* tgt_in  = (const int*)d_in[4];
    const int* tgt_tag = (const int*)d_in[5];
    const float* emb      = (const float*)d_in[6];
    const float* enc_Wih  = (const float*)d_in[7];
    const float* enc_Whh  = (const float*)d_in[8];
    const float* enc_bih  = (const float*)d_in[9];
    const float* enc_bhh  = (const float*)d_in[10];
    const float* dec_Wih  = (const float*)d_in[11];
    const float* dec_Whh  = (const float*)d_in[12];
    const float* dec_bih  = (const float*)d_in[13];
    const float* dec_bhh  = (const float*)d_in[14];
    const float* state_W  = (const float*)d_in[15];
    const float* state_b  = (const float*)d_in[16];
    const float* noun_W   = (const float*)d_in[17];
    const float* noun_b   = (const float*)d_in[18];
    const float* verb_W   = (const float*)d_in[19];
    const float* verb_b   = (const float*)d_in[20];
    const float* pron_W   = (const float*)d_in[21];
    const float* pron_b   = (const float*)d_in[22];
    const float* sen_W    = (const float*)d_in[23];
    const float* sen_b    = (const float*)d_in[24];

    float* out = (float*)d_out;
    char* ws = (char*)d_ws;

    // ws layout (bytes), total ~19.73 MB
    float* enc_xg  = (float*)(ws + 0);                       // 4*512*900 f = 7372800
    float* dec_xg  = (float*)(ws + 7372800);                 // 2048*900 f  = 7372800
    u64*   hs_tag  = (u64*)  (ws + 14745600);                // 2048*300 u64 = 4915200
    int*   enc_ids = (int*)  (ws + 19660800);                // 8192
    int*   lists   = (int*)  (ws + 19668992);                // 4*2048 i = 32768
    int*   counts  = (int*)  (ws + 19701760);                // 64
    u64*   hbuf    = (u64*)  (ws + 19701824);                // 5*2*300 u64 = 24000
    int*   tile_ctr= (int*)  (ws + 19725824);                // 64
    // hs_tag is NOT zeroed: poison 0xAAAAAAAA can never equal tag step+2.

    // zero hbuf (ver 0 == encoder h0 == 0.0f) + tile counter in one memset
    hipMemsetAsync(ws + 19701824, 0, 24000 + 64, stream);

    prep_ids_kernel<<<8, 256, 0, stream>>>(verb_in, pron_in, noun_in, sen_in, enc_ids);

    // xg = emb[ids] @ Wih.T + bih   (enc: 4x512 rows; dec: 2048 rows)
    gemm_gather_kernel<<<dim3(15, 32), 256, 0, stream>>>(
        emb, enc_Wih, enc_bih, enc_ids, 4 * TENC, G3, enc_xg);
    gemm_gather_kernel<<<dim3(15, 32), 256, 0, stream>>>(
        emb, dec_Wih, dec_bih, tgt_in, TDEC, G3, dec_xg);

    bucket_kernel<<<1, 256, 0, stream>>>(tgt_tag, lists, counts);

    gru_rnn_kernel<<<8 * KWG, 256, 0, stream>>>(
        enc_xg, dec_xg, enc_Whh, enc_bhh, dec_Whh, dec_bhh,
        state_W, state_b, hs_tag, hbuf, lists, counts, tile_ctr,
        noun_W, noun_b, verb_W, verb_b, pron_W, pron_b, sen_W, sen_b, out);
}